// Round 1
// baseline (337.238 us; speedup 1.0000x reference)
//
#include <hip/hip_runtime.h>

// MultiConvPerm: out[co,ci,t] over (256,256,1024) f32.
// coef = softmax(alpha + gumbels)  (log_softmax shift cancels under softmax)
// acc[s], s in [0,57): sum of 72 static taps coef[i]*w_i[pair,j] at s = p_i + j*d_i
// flip+roll collapses to: out[t] = acc[28-t] (t<=28), acc[1052-t] (t>=996), else 0.
//
// Split design (evidence: harness's fillBufferAligned runs at 6.3 TB/s on this
// exact buffer; our fused gather+stream kernel ran at ~1.7 TB/s effective):
//   1. fill_zero: plain float4 grid-stride zero of all 268 MB (memset-shaped).
//   2. multiconv_edges: writes only the 15 nonzero float4 slots per 1024-float
//      row (slots 0..7 and 249..255), values gathered from a per-block LDS acc.

#define NW 12
#define PAIRS_PER_BLOCK 16
#define OUT_FLOAT4 (256u * 256u * 1024u / 4u)  // 16,777,216 float4s = 268 MB

typedef float vfloat4 __attribute__((ext_vector_type(4)));

__global__ __launch_bounds__(256) void fill_zero(vfloat4* __restrict__ out) {
    size_t i = (size_t)blockIdx.x * 256 + threadIdx.x;
    const size_t stride = (size_t)gridDim.x * 256;
    const vfloat4 z = (vfloat4)0.f;
#pragma unroll 4
    for (; i < OUT_FLOAT4; i += stride) out[i] = z;
}

__global__ __launch_bounds__(256) void multiconv_edges(
    const float* __restrict__ w0,  const float* __restrict__ w1,
    const float* __restrict__ w2,  const float* __restrict__ w3,
    const float* __restrict__ w4,  const float* __restrict__ w5,
    const float* __restrict__ w6,  const float* __restrict__ w7,
    const float* __restrict__ w8,  const float* __restrict__ w9,
    const float* __restrict__ w10, const float* __restrict__ w11,
    const float* __restrict__ alpha, const float* __restrict__ gumbels,
    float* __restrict__ out) {
    __shared__ float acc[PAIRS_PER_BLOCK][57];
    __shared__ float cf[NW];
    const int tid = threadIdx.x;
    const int p0  = blockIdx.x * PAIRS_PER_BLOCK;

    // zero the accumulator tile
    float* af = &acc[0][0];
    for (int i = tid; i < PAIRS_PER_BLOCK * 57; i += 256) af[i] = 0.f;

    // redundant per-block softmax (alpha/gumbels are 12 floats, L2-hot)
    if (tid < NW) {
        float m = -1e30f;
#pragma unroll
        for (int i = 0; i < NW; ++i) m = fmaxf(m, alpha[i] + gumbels[i]);
        float s = 0.f;
#pragma unroll
        for (int i = 0; i < NW; ++i) s += expf(alpha[i] + gumbels[i] - m);
        cf[tid] = expf(alpha[tid] + gumbels[tid] - m) / s;
    }
    __syncthreads();

    // Coalesced weight loads: threads t < 16*k read w_i[p0*k + t] contiguously.
    // pair_local = t/k, tap j = t%k; tap lands at s = p + j*d.
    // Cross-array overlaps at the same (pair,s) are resolved by LDS atomics.
#define TAP(WP, I, K, P, D)                                                   \
    if (tid < PAIRS_PER_BLOCK * (K)) {                                        \
        int pl = tid / (K), j = tid % (K);                                    \
        atomicAdd(&acc[pl][(P) + j * (D)],                                    \
                  cf[I] * WP[(size_t)p0 * (K) + tid]);                        \
    }
    TAP(w0,  0, 3, 27, 1)
    TAP(w1,  1, 3, 25, 3)
    TAP(w2,  2, 3, 21, 7)
    TAP(w3,  3, 5, 26, 1)
    TAP(w4,  4, 5, 22, 3)
    TAP(w5,  5, 5, 14, 7)
    TAP(w6,  6, 7, 25, 1)
    TAP(w7,  7, 7, 19, 3)
    TAP(w8,  8, 7,  7, 7)
    TAP(w9,  9, 9, 24, 1)
    TAP(w10, 10, 9, 16, 3)
    TAP(w11, 11, 9,  0, 7)
#undef TAP
    __syncthreads();

    // 16 rows/block; 15 nonzero float4 slots per row: 0..7 and 249..255.
    // thread = r*15 + sidx, 240 active threads, one float4 store each.
    if (tid < PAIRS_PER_BLOCK * 15) {
        const int r    = tid / 15;
        const int sidx = tid % 15;
        const int slot = (sidx < 8) ? sidx : (241 + sidx);  // 8..14 -> 249..255
        const float* a = acc[r];
        vfloat4 v = (vfloat4)0.f;
        if (slot < 7) {                      // t = 4*slot..4*slot+3, s = 28-t
            int t0 = slot * 4;
            v.x = a[28 - t0]; v.y = a[27 - t0]; v.z = a[26 - t0]; v.w = a[25 - t0];
        } else if (slot == 7) {              // t=28 -> s=0; t=29..31 stay zero
            v.x = a[0];
        } else {                             // t=996..1023 -> s = 1052-t (29..56)
            int t0 = slot * 4;
            v.x = a[1052 - t0]; v.y = a[1051 - t0]; v.z = a[1050 - t0]; v.w = a[1049 - t0];
        }
        reinterpret_cast<vfloat4*>(out)[(size_t)(p0 + r) * 256 + slot] = v;
    }
}

extern "C" void kernel_launch(void* const* d_in, const int* in_sizes, int n_in,
                              void* d_out, int out_size, void* d_ws, size_t ws_size,
                              hipStream_t stream) {
    // 1) bulk zero: 2048 blocks x 256 threads, 32 float4 stores/thread
    fill_zero<<<2048, 256, 0, stream>>>(reinterpret_cast<vfloat4*>(d_out));
    // 2) edges: one block per 16 (co,ci) pairs
    multiconv_edges<<<(256 * 256) / PAIRS_PER_BLOCK, 256, 0, stream>>>(
        (const float*)d_in[0], (const float*)d_in[1], (const float*)d_in[2],
        (const float*)d_in[3], (const float*)d_in[4], (const float*)d_in[5],
        (const float*)d_in[6], (const float*)d_in[7], (const float*)d_in[8],
        (const float*)d_in[9], (const float*)d_in[10], (const float*)d_in[11],
        (const float*)d_in[12], (const float*)d_in[13], (float*)d_out);
}

// Round 2
// 331.747 us; speedup vs baseline: 1.0166x; 1.0166x over previous
//
#include <hip/hip_runtime.h>

// MultiConvPerm: out[co,ci,t] over (256,256,1024) f32, fused single pass.
// coef = softmax(alpha + gumbels)  (log_softmax shift cancels under softmax)
// acc[s], s in [0,57): sum of 72 static taps coef[i]*w_i[pair,j] at s = p_i + j*d_i
// flip+roll collapses to: out[t] = acc[28-t] (t<=28), acc[1052-t] (t>=996), else 0.
//
// Round-1 lesson: splitting into memset-clone + edges kernel LOST (337 vs 325):
// dur_us is dominated by a fixed harness component (~265 us: 1 GiB poison fill
// + reset dispatches); the fused kernel's marginal cost (~55 us) was already
// near the 268 MB write floor (~43 us @ 6.3 TB/s). So: one dispatch, and
// restructure stores so the 94%-zero middle stream is branch-free and issued
// while the weight loads are still in flight.

#define NW 12
#define PAIRS_PER_BLOCK 16

typedef float vfloat4 __attribute__((ext_vector_type(4)));

__global__ __launch_bounds__(256) void multiconv_fused(
    const float* __restrict__ w0,  const float* __restrict__ w1,
    const float* __restrict__ w2,  const float* __restrict__ w3,
    const float* __restrict__ w4,  const float* __restrict__ w5,
    const float* __restrict__ w6,  const float* __restrict__ w7,
    const float* __restrict__ w8,  const float* __restrict__ w9,
    const float* __restrict__ w10, const float* __restrict__ w11,
    const float* __restrict__ alpha, const float* __restrict__ gumbels,
    float* __restrict__ out) {
    __shared__ float acc[PAIRS_PER_BLOCK][57];
    __shared__ float cf[NW];
    const int tid = threadIdx.x;
    const int p0  = blockIdx.x * PAIRS_PER_BLOCK;

    // zero the accumulator tile
    float* af = &acc[0][0];
    for (int i = tid; i < PAIRS_PER_BLOCK * 57; i += 256) af[i] = 0.f;

    // redundant per-block softmax (alpha/gumbels are 12 floats, L2-hot)
    if (tid < NW) {
        float m = -1e30f;
#pragma unroll
        for (int i = 0; i < NW; ++i) m = fmaxf(m, alpha[i] + gumbels[i]);
        float s = 0.f;
#pragma unroll
        for (int i = 0; i < NW; ++i) s += expf(alpha[i] + gumbels[i] - m);
        cf[tid] = expf(alpha[tid] + gumbels[tid] - m) / s;
    }
    __syncthreads();

    // Coalesced weight loads: threads t < 16*k read w_i[p0*k + t] contiguously.
    // pair_local = t/k, tap j = t%k; tap lands at s = p + j*d.
    // Cross-array overlaps at the same (pair,s) are resolved by LDS atomics.
#define TAP(WP, I, K, P, D)                                                   \
    if (tid < PAIRS_PER_BLOCK * (K)) {                                        \
        int pl = tid / (K), j = tid % (K);                                    \
        atomicAdd(&acc[pl][(P) + j * (D)],                                    \
                  cf[I] * WP[(size_t)p0 * (K) + tid]);                        \
    }
    TAP(w0,  0, 3, 27, 1)
    TAP(w1,  1, 3, 25, 3)
    TAP(w2,  2, 3, 21, 7)
    TAP(w3,  3, 5, 26, 1)
    TAP(w4,  4, 5, 22, 3)
    TAP(w5,  5, 5, 14, 7)
    TAP(w6,  6, 7, 25, 1)
    TAP(w7,  7, 7, 19, 3)
    TAP(w8,  8, 7,  7, 7)
    TAP(w9,  9, 9, 24, 1)
    TAP(w10, 10, 9, 16, 3)
    TAP(w11, 11, 9,  0, 7)
#undef TAP

    // Middle slots 8..248 of every row are always zero: branch-free NT zero
    // stream, issued while the weight loads/atomics above are still draining.
    vfloat4* outv = reinterpret_cast<vfloat4*>(out) + (size_t)p0 * 256 + tid;
    if (tid >= 8 && tid <= 248) {
        const vfloat4 z = (vfloat4)0.f;
#pragma unroll
        for (int r = 0; r < PAIRS_PER_BLOCK; ++r)
            __builtin_nontemporal_store(z, outv + (size_t)r * 256);
    }
    __syncthreads();

    // Edge slots: 15 nonzero float4 slots per row (0..7 and 249..255),
    // one store per thread over 240 threads.
    if (tid < PAIRS_PER_BLOCK * 15) {
        const int r    = tid / 15;
        const int sidx = tid % 15;
        const int slot = (sidx < 8) ? sidx : (241 + sidx);  // 8..14 -> 249..255
        const float* a = acc[r];
        vfloat4 v = (vfloat4)0.f;
        if (slot < 7) {                      // t = 4*slot..4*slot+3, s = 28-t
            int t0 = slot * 4;
            v.x = a[28 - t0]; v.y = a[27 - t0]; v.z = a[26 - t0]; v.w = a[25 - t0];
        } else if (slot == 7) {              // t=28 -> s=0; t=29..31 stay zero
            v.x = a[0];
        } else {                             // t=996..1023 -> s = 1052-t (29..56)
            int t0 = slot * 4;
            v.x = a[1052 - t0]; v.y = a[1051 - t0]; v.z = a[1050 - t0]; v.w = a[1049 - t0];
        }
        __builtin_nontemporal_store(
            v, reinterpret_cast<vfloat4*>(out) + (size_t)(p0 + r) * 256 + slot);
    }
}

extern "C" void kernel_launch(void* const* d_in, const int* in_sizes, int n_in,
                              void* d_out, int out_size, void* d_ws, size_t ws_size,
                              hipStream_t stream) {
    multiconv_fused<<<(256 * 256) / PAIRS_PER_BLOCK, 256, 0, stream>>>(
        (const float*)d_in[0], (const float*)d_in[1], (const float*)d_in[2],
        (const float*)d_in[3], (const float*)d_in[4], (const float*)d_in[5],
        (const float*)d_in[6], (const float*)d_in[7], (const float*)d_in[8],
        (const float*)d_in[9], (const float*)d_in[10], (const float*)d_in[11],
        (const float*)d_in[12], (const float*)d_in[13], (float*)d_out);
}